// Round 9
// baseline (619.911 us; speedup 1.0000x reference)
//
#include <hip/hip_runtime.h>

typedef _Float16 half8_t __attribute__((ext_vector_type(8)));
typedef _Float16 half4_t __attribute__((ext_vector_type(4)));
typedef float floatx4 __attribute__((ext_vector_type(4)));

#define S_LEN 2048
#define U_DIM 1024
#define HD 128
#define M_TOT 8192
#define NHEADS 32

// RAW-RESHAPE MAPPING (reference does reshape(B*H,S,HD), a flat reinterpret):
//   (b,s,u) -> head n = b*8 + (s>>8), sq = (s&255)*8 + (u>>7), d = u&127.
// Any buffer stored flat [b][s][u] can be read as [n][sq][d] directly.

// Barrier that drains LDS ops only — in-flight global loads (vmcnt) cross it.
// __syncthreads() would force s_waitcnt vmcnt(0) and stall on the prefetch.
__device__ __forceinline__ void barrier_lgkm() {
    __asm__ volatile("s_waitcnt lgkmcnt(0)\ns_barrier" ::: "memory");
}

// XOR-swizzle for a 16-row x 64B chunk (coalesced global source, conflict-free
// LDS fragment reads).
__device__ __forceinline__ int swz(int row) { return (row >> 1) & 3; }

// ---------------------------------------------------------------------------
// x (fp32, 8192x1024) -> f16
__global__ __launch_bounds__(256) void k_convert_x(const float* __restrict__ x,
                                                   _Float16* __restrict__ xh) {
    size_t i = (size_t)blockIdx.x * 256 + threadIdx.x;
    float4 v = ((const float4*)x)[i];
    half4_t h;
    h[0] = (_Float16)v.x; h[1] = (_Float16)v.y;
    h[2] = (_Float16)v.z; h[3] = (_Float16)v.w;
    ((half4_t*)xh)[i] = h;
}

// ---------------------------------------------------------------------------
// W (fp32, [k][n]) -> wt f16 [z][n][k]  (transposed, for B-fragments)
__global__ __launch_bounds__(256) void k_transpose_w(const float* __restrict__ Wq,
                                                     const float* __restrict__ Wk,
                                                     const float* __restrict__ Wv,
                                                     const float* __restrict__ Wr,
                                                     _Float16* __restrict__ wt) {
    const int z = blockIdx.z;
    const float* W = (z == 0) ? Wq : (z == 1) ? Wk : (z == 2) ? Wv : Wr;
    _Float16* o = wt + (size_t)z * U_DIM * U_DIM;
    __shared__ float t[64][65];
    const int n0 = blockIdx.x * 64, k0 = blockIdx.y * 64;
    const int tid = threadIdx.x;
    for (int c = tid; c < 1024; c += 256) {
        int kk = c >> 4, nn = (c & 15) * 4;
        float4 v = *(const float4*)&W[(size_t)(k0 + kk) * U_DIM + n0 + nn];
        t[kk][nn] = v.x; t[kk][nn + 1] = v.y; t[kk][nn + 2] = v.z; t[kk][nn + 3] = v.w;
    }
    __syncthreads();
    for (int c = tid; c < 512; c += 256) {
        int nn = c >> 3, ks = (c & 7) * 8;
        half8_t h;
        for (int i = 0; i < 8; i++) h[i] = (_Float16)t[ks + i][nn];
        *(half8_t*)&o[(size_t)(n0 + nn) * U_DIM + k0 + ks] = h;
    }
}

// ---------------------------------------------------------------------------
// C = relu(X @ W_z + b_z), f16 row-major out. 128x128 tile; register-relay
// staging (global->VGPR->ds_write) with lgkm-only barriers so the next tile's
// global loads stay in flight across both barriers.
__global__ __launch_bounds__(256) void k_qkvr_gemm(const _Float16* __restrict__ xh,
                                                   const _Float16* __restrict__ wt,
                                                   const float* __restrict__ bq,
                                                   const float* __restrict__ bk,
                                                   const float* __restrict__ bv,
                                                   const float* __restrict__ br,
                                                   _Float16* __restrict__ qh,
                                                   _Float16* __restrict__ kh,
                                                   _Float16* __restrict__ vh,
                                                   _Float16* __restrict__ resh) {
    const int b = blockIdx.x;
    const int xcd = b & 7, s = b >> 3;
    const int pair = xcd + 8 * (s & 3);       // (z,n) column pair, fixed per XCD slot
    const int m0 = (s >> 2) * 128;
    const int n0 = (pair & 7) * 128;
    const int z = pair >> 3;
    const _Float16* wz = wt + (size_t)z * U_DIM * U_DIM;

    __shared__ __align__(16) char AsB[8192];   // 8 chunks of 16 rows x 64B, swizzled
    __shared__ __align__(16) char BsB[8192];
    __shared__ __align__(16) _Float16 Cs[128][136];

    const int tid = threadIdx.x;
    const int wave = tid >> 6, lane = tid & 63;
    const int lrow = lane & 15, quad = lane >> 4;
    const int wm = (wave >> 1) * 64, wn = (wave & 1) * 64;
    const int lr4 = lane >> 2;
    const int sseg = ((lane & 3) ^ swz(lr4)) * 16;  // swizzled source segment
    const int rsw = (quad ^ swz(lrow)) * 16;        // swizzled read segment

    floatx4 acc[4][4];
    for (int i = 0; i < 4; i++)
        for (int j = 0; j < 4; j++) acc[i][j] = (floatx4)0.0f;

    // per-lane source bases (row = c*16 + lr4, swizzled 16B segment)
    const char* xsrc = (const char*)xh + (size_t)(m0 + wave * 32 + lr4) * 2048 + sseg;
    const char* wsrc = (const char*)wz + (size_t)(n0 + wave * 32 + lr4) * 2048 + sseg;

    float4 areg[2], breg[2];
    for (int t = 0; t < 2; t++) {
        areg[t] = *(const float4*)(xsrc + t * 16 * 2048);
        breg[t] = *(const float4*)(wsrc + t * 16 * 2048);
    }

    for (int k0 = 0; k0 < U_DIM; k0 += 32) {
        for (int t = 0; t < 2; t++) {
            *(float4*)(AsB + (wave * 2 + t) * 1024 + lane * 16) = areg[t];
            *(float4*)(BsB + (wave * 2 + t) * 1024 + lane * 16) = breg[t];
        }
        barrier_lgkm();
        if (k0 + 32 < U_DIM) {
            for (int t = 0; t < 2; t++) {
                areg[t] = *(const float4*)(xsrc + t * 16 * 2048 + (k0 + 32) * 2);
                breg[t] = *(const float4*)(wsrc + t * 16 * 2048 + (k0 + 32) * 2);
            }
        }
        half8_t af[4], bf[4];
        for (int i = 0; i < 4; i++)
            af[i] = *(const half8_t*)(AsB + ((wave >> 1) * 4 + i) * 1024 + lrow * 64 + rsw);
        for (int j = 0; j < 4; j++)
            bf[j] = *(const half8_t*)(BsB + ((wave & 1) * 4 + j) * 1024 + lrow * 64 + rsw);
        for (int i = 0; i < 4; i++)
            for (int j = 0; j < 4; j++)
                acc[i][j] = __builtin_amdgcn_mfma_f32_16x16x32_f16(af[i], bf[j], acc[i][j], 0, 0, 0);
        barrier_lgkm();
    }

    const float* bias = (z == 0) ? bq : (z == 1) ? bk : (z == 2) ? bv : br;
    _Float16* dst = (z == 0) ? qh : (z == 1) ? kh : (z == 2) ? vh : resh;

    for (int i = 0; i < 4; i++) {
        for (int j = 0; j < 4; j++) {
            int col = wn + j * 16 + lrow;
            float bcol = bias[n0 + col];
            for (int r = 0; r < 4; r++) {
                float v = acc[i][j][r] + bcol;
                Cs[wm + i * 16 + quad * 4 + r][col] = (_Float16)(v > 0.f ? v : 0.f);
            }
        }
    }
    __syncthreads();
    for (int c = tid; c < 2048; c += 256) {
        int row = c >> 4, seg = (c & 15) * 8;
        *(half8_t*)&dst[(size_t)(m0 + row) * U_DIM + n0 + seg] = *(half8_t*)&Cs[row][seg];
    }
}

// ---------------------------------------------------------------------------
// v (f16 flat, read as [n][s][d] per raw reshape) -> vt (f16, [n][d][s])
__global__ __launch_bounds__(256) void k_transpose_v(const _Float16* __restrict__ vh,
                                                     _Float16* __restrict__ vt) {
    const int n = blockIdx.z;
    const int s0 = blockIdx.x * 64, d0 = blockIdx.y * 64;
    const _Float16* V = vh + (size_t)n * S_LEN * HD;
    _Float16* O = vt + (size_t)n * HD * S_LEN;
    __shared__ _Float16 t[64][72];
    const int tid = threadIdx.x;
    for (int c = tid; c < 512; c += 256) {
        int srow = c >> 3, off = (c & 7) * 8;
        *(half8_t*)&t[srow][off] = *(const half8_t*)&V[(size_t)(s0 + srow) * HD + d0 + off];
    }
    __syncthreads();
    for (int c = tid; c < 512; c += 256) {
        int drow = c >> 3, soff = (c & 7) * 8;
        half8_t h;
        for (int i = 0; i < 8; i++) h[i] = t[soff + i][drow];
        *(half8_t*)&O[(size_t)(d0 + drow) * S_LEN + s0 + soff] = h;
    }
}

// ---------------------------------------------------------------------------
// Fused attention v6: KV-split x2; 4 waves x 32 q-rows; register-relay
// staging + lgkm-only barriers (prefetch loads cross the barriers).
// S^T = K @ Q^T -> packed P writes. Unnormalized softmax p = exp2(s*C1 - 6)
// (shift cancels at combine). Emits unnormalized partial O (f32) + row-sums l.
__global__ __launch_bounds__(256, 2) void k_flash(const _Float16* __restrict__ qh,
                                                  const _Float16* __restrict__ kh,
                                                  const _Float16* __restrict__ vt,
                                                  float* __restrict__ Opart,
                                                  float* __restrict__ lpart) {
    const int head = blockIdx.x + 8 * (blockIdx.y & 3);
    const int m0 = (int)(blockIdx.y >> 2) * 128;
    const int kv2 = blockIdx.z;                 // kv half: kt in [kv2*16, kv2*16+16)
    const _Float16* Q = qh + (size_t)head * S_LEN * HD;
    const char* Kb = (const char*)(kh + (size_t)head * S_LEN * HD);
    const char* Vb = (const char*)(vt + (size_t)head * HD * S_LEN);

    __shared__ __align__(16) char smem[51200];
    _Float16* Ps = (_Float16*)(smem + 32768);  // [128 q][72 kv halves]

    const int tid = threadIdx.x;
    const int w = tid >> 6, lane = tid & 63;
    const int lrow = lane & 15, quad = lane >> 4;
    const int lr4 = lane >> 2;
    const int sseg = ((lane & 3) ^ swz(lr4)) * 16;
    const int rsw = (quad ^ swz(lrow)) * 16;

    half8_t qf[2][4];
    for (int i = 0; i < 2; i++)
        for (int k0 = 0; k0 < 4; k0++)
            qf[i][k0] = *(const half8_t*)&Q[(size_t)(m0 + w * 32 + i * 16 + lrow) * HD + k0 * 32 + quad * 8];

    floatx4 acc_o[2][8];
    for (int i = 0; i < 2; i++)
        for (int j = 0; j < 8; j++) acc_o[i][j] = (floatx4)0.0f;
    float lp[2] = {0.0f, 0.0f};  // row-sums for q = w*32 + i*16 + lrow

    const float C1 = 0.12751742f;  // (1/sqrt(128)) * log2(e)
    const int kt0 = kv2 * 16, kt_end = kt0 + 16;

    // per-lane prefetch source bases:
    //  K chunk c=w*4+t: k0=c>>2, j=c&3 -> row kt*64 + j*16 + lr4, seg k0*64+sseg
    //  V chunk c=w*4+t: k0s=c>>3, dg=c&7 -> row dg*16+lr4, seg kt*128 + k0s*64+sseg
    const char* ksrc[4];
    const char* vsrc[4];
    for (int t = 0; t < 4; t++) {
        int c = w * 4 + t;
        ksrc[t] = Kb + (size_t)((c & 3) * 16 + lr4) * 256 + (c >> 2) * 64 + sseg;
        vsrc[t] = Vb + (size_t)((c & 7) * 16 + lr4) * 4096 + (c >> 3) * 64 + sseg;
    }

    float4 kreg[4], vreg[4];
    for (int t = 0; t < 4; t++) {
        kreg[t] = *(const float4*)(ksrc[t] + (size_t)kt0 * 16384);
        vreg[t] = *(const float4*)(vsrc[t] + kt0 * 128);
    }

    for (int kt = kt0; kt < kt_end; ++kt) {
        for (int t = 0; t < 4; t++) {
            *(float4*)(smem + (w * 4 + t) * 1024 + lane * 16) = kreg[t];
            *(float4*)(smem + 16384 + (w * 4 + t) * 1024 + lane * 16) = vreg[t];
        }
        barrier_lgkm();
        if (kt + 1 < kt_end) {
            for (int t = 0; t < 4; t++) {
                kreg[t] = *(const float4*)(ksrc[t] + (size_t)(kt + 1) * 16384);
                vreg[t] = *(const float4*)(vsrc[t] + (kt + 1) * 128);
            }
        }

        // S^T tiles: T[kv 16][q 16]; lane holds kv=j*16+quad*4+r, q=lrow
        floatx4 acc_t[2][4];
        for (int i = 0; i < 2; i++)
            for (int j = 0; j < 4; j++) acc_t[i][j] = (floatx4)0.0f;
        for (int k0 = 0; k0 < 4; k0++)
            for (int j = 0; j < 4; j++) {
                half8_t kf = *(const half8_t*)(smem + (k0 * 4 + j) * 1024 + lrow * 64 + rsw);
                for (int i = 0; i < 2; i++)
                    acc_t[i][j] = __builtin_amdgcn_mfma_f32_16x16x32_f16(kf, qf[i][k0], acc_t[i][j], 0, 0, 0);
            }

        // exp + packed P write (ds_write_b64: 4 consecutive kv per lane)
        for (int i = 0; i < 2; i++)
            for (int j = 0; j < 4; j++) {
                floatx4 sv = acc_t[i][j] * C1 - 6.0f;
                half4_t ph;
                float p0 = exp2f(sv[0]), p1 = exp2f(sv[1]);
                float p2 = exp2f(sv[2]), p3 = exp2f(sv[3]);
                ph[0] = (_Float16)p0; ph[1] = (_Float16)p1;
                ph[2] = (_Float16)p2; ph[3] = (_Float16)p3;
                lp[i] += (p0 + p1) + (p2 + p3);
                *(half4_t*)&Ps[(w * 32 + i * 16 + lrow) * 72 + j * 16 + quad * 4] = ph;
            }

        // PV: O[32 q x 128 d] += P[32 x 64] @ V[64 x 128]
        for (int k0s = 0; k0s < 2; k0s++) {
            half8_t af[2];
            for (int i = 0; i < 2; i++)
                af[i] = *(const half8_t*)&Ps[(w * 32 + i * 16 + lrow) * 72 + k0s * 32 + quad * 8];
            for (int j = 0; j < 8; j++) {
                half8_t bv = *(const half8_t*)(smem + 16384 + (k0s * 8 + j) * 1024 + lrow * 64 + rsw);
                for (int i = 0; i < 2; i++)
                    acc_o[i][j] = __builtin_amdgcn_mfma_f32_16x16x32_f16(af[i], bv, acc_o[i][j], 0, 0, 0);
            }
        }
        barrier_lgkm();
    }

    // reduce row sums across quads (all lanes end with total for q=w*32+i*16+lrow)
    for (int i = 0; i < 2; i++) {
        lp[i] += __shfl_xor(lp[i], 16, 64);
        lp[i] += __shfl_xor(lp[i], 32, 64);
    }

    // unnormalized partial O (f32, flat [head][sq][d]) + partial l
    float* Od = Opart + (size_t)kv2 * ((size_t)NHEADS * S_LEN * HD) +
                ((size_t)head * S_LEN + m0) * HD;
    for (int i = 0; i < 2; i++)
        for (int j = 0; j < 8; j++)
            for (int r = 0; r < 4; r++)
                Od[(size_t)(w * 32 + i * 16 + quad * 4 + r) * HD + j * 16 + lrow] = acc_o[i][j][r];
    float* Ld = lpart + (size_t)kv2 * (NHEADS * S_LEN) + head * S_LEN + m0;
    if (quad == 0) {
        Ld[w * 32 + lrow] = lp[0];
        Ld[w * 32 + 16 + lrow] = lp[1];
    }
}

// ---------------------------------------------------------------------------
// out = LN(relu((Oa+Ob)/(la+lb) + res)) * gamma + beta ; biased var.
// Flat indexing throughout (raw reshape); l index for flat element e is e>>7.
__global__ __launch_bounds__(256) void k_ln(const float* __restrict__ Opart,
                                            const float* __restrict__ lpart,
                                            const _Float16* __restrict__ resh,
                                            const float* __restrict__ gamma,
                                            const float* __restrict__ beta,
                                            float* __restrict__ out) {
    const int row = blockIdx.x;            // flat row of the (8192,1024) matrix
    const int tid = threadIdx.x;
    const size_t e = (size_t)row * U_DIM + tid * 4;
    const size_t OH = (size_t)M_TOT * U_DIM;
    const int lidx = row * 8 + (tid >> 5);          // = e >> 7

    float4 a4 = *(const float4*)&Opart[e];
    float4 b4 = *(const float4*)&Opart[OH + e];
    float l = lpart[lidx] + lpart[NHEADS * S_LEN + lidx];
    float inv = 1.0f / l;
    half4_t rv = ((const half4_t*)(resh))[e >> 2];
    float4 gv = ((const float4*)gamma)[tid];
    float4 bv = ((const float4*)beta)[tid];

    float o[4];
    o[0] = fmaxf((a4.x + b4.x) * inv + (float)rv[0], 0.f);
    o[1] = fmaxf((a4.y + b4.y) * inv + (float)rv[1], 0.f);
    o[2] = fmaxf((a4.z + b4.z) * inv + (float)rv[2], 0.f);
    o[3] = fmaxf((a4.w + b4.w) * inv + (float)rv[3], 0.f);

    float s1 = (o[0] + o[1]) + (o[2] + o[3]);
    float s2 = (o[0] * o[0] + o[1] * o[1]) + (o[2] * o[2] + o[3] * o[3]);
    for (int off = 32; off; off >>= 1) {
        s1 += __shfl_xor(s1, off, 64);
        s2 += __shfl_xor(s2, off, 64);
    }
    __shared__ float red[8];
    const int wv = tid >> 6;
    if ((tid & 63) == 0) { red[wv] = s1; red[4 + wv] = s2; }
    __syncthreads();
    float ts1 = red[0] + red[1] + red[2] + red[3];
    float ts2 = red[4] + red[5] + red[6] + red[7];
    float mean = ts1 * (1.0f / 1024.0f);
    float var = ts2 * (1.0f / 1024.0f) - mean * mean;
    float rstd = rsqrtf(var + 1e-8f);
    float4 ov;
    ov.x = gv.x * (o[0] - mean) * rstd + bv.x;
    ov.y = gv.y * (o[1] - mean) * rstd + bv.y;
    ov.z = gv.z * (o[2] - mean) * rstd + bv.z;
    ov.w = gv.w * (o[3] - mean) * rstd + bv.w;
    ((float4*)(out))[e >> 2] = ov;
}

// ---------------------------------------------------------------------------
extern "C" void kernel_launch(void* const* d_in, const int* in_sizes, int n_in,
                              void* d_out, int out_size, void* d_ws, size_t ws_size,
                              hipStream_t stream) {
    const float* x     = (const float*)d_in[0];
    const float* Wq    = (const float*)d_in[1];
    const float* bq    = (const float*)d_in[2];
    const float* Wk    = (const float*)d_in[3];
    const float* bk    = (const float*)d_in[4];
    const float* Wv    = (const float*)d_in[5];
    const float* bv    = (const float*)d_in[6];
    const float* Wr    = (const float*)d_in[7];
    const float* br    = (const float*)d_in[8];
    const float* gamma = (const float*)d_in[9];
    const float* beta  = (const float*)d_in[10];
    float* out = (float*)d_out;

    char* p = (char*)d_ws;
    _Float16* xh = (_Float16*)p;    p += (size_t)M_TOT * U_DIM * 2;       // 16 MB
    _Float16* wt = (_Float16*)p;    p += (size_t)4 * U_DIM * U_DIM * 2;   //  8 MB
    _Float16* qh = (_Float16*)p;    p += (size_t)M_TOT * U_DIM * 2;       // 16 MB
    _Float16* kh = (_Float16*)p;    p += (size_t)M_TOT * U_DIM * 2;       // 16 MB
    _Float16* vh = (_Float16*)p;    p += (size_t)M_TOT * U_DIM * 2;       // 16 MB
    _Float16* vt = (_Float16*)p;    p += (size_t)M_TOT * U_DIM * 2;       // 16 MB
    _Float16* resh = (_Float16*)p;  p += (size_t)M_TOT * U_DIM * 2;       // 16 MB
    float* Opart = (float*)p;       p += (size_t)2 * M_TOT * U_DIM * 4;   // 64 MB
    float* lpart = (float*)p;                                             // 512 KB

    k_convert_x<<<8192, 256, 0, stream>>>(x, xh);
    k_transpose_w<<<dim3(16, 16, 4), 256, 0, stream>>>(Wq, Wk, Wv, Wr, wt);
    k_qkvr_gemm<<<2048, 256, 0, stream>>>(xh, wt, bq, bk, bv, br, qh, kh, vh, resh);
    k_transpose_v<<<dim3(32, 2, 32), 256, 0, stream>>>(vh, vt);
    k_flash<<<dim3(8, 64, 2), 256, 0, stream>>>(qh, kh, vt, Opart, lpart);
    k_ln<<<8192, 256, 0, stream>>>(Opart, lpart, resh, gamma, beta, out);
}

// Round 10
// 299.462 us; speedup vs baseline: 2.0701x; 2.0701x over previous
//
#include <hip/hip_runtime.h>

typedef _Float16 half8_t __attribute__((ext_vector_type(8)));
typedef _Float16 half4_t __attribute__((ext_vector_type(4)));
typedef float floatx4 __attribute__((ext_vector_type(4)));

#define S_LEN 2048
#define U_DIM 1024
#define HD 128
#define M_TOT 8192
#define NHEADS 32

// RAW-RESHAPE MAPPING (reference does reshape(B*H,S,HD), a flat reinterpret):
//   (b,s,u) -> head n = b*8 + (s>>8), sq = (s&255)*8 + (u>>7), d = u&127.
// Any buffer stored flat [b][s][u] can be read as [n][sq][d] directly.

// glds: async global->LDS, 16B/lane. lds_base must be wave-uniform; g is per-lane.
__device__ __forceinline__ void stage16(void* lds_base, const void* g_lane, int lane) {
#if defined(__has_builtin) && __has_builtin(__builtin_amdgcn_global_load_lds)
    __builtin_amdgcn_global_load_lds(
        (const __attribute__((address_space(1))) unsigned int*)g_lane,
        (__attribute__((address_space(3))) unsigned int*)lds_base, 16, 0, 0);
#else
    *(float4*)((char*)lds_base + lane * 16) = *(const float4*)g_lane;
#endif
}

// XOR-swizzle for a 16-row x 64B chunk staged via glds (coalesced global
// source, 2-way-max LDS fragment reads).
__device__ __forceinline__ int swz(int row) { return (row >> 1) & 3; }

// ---------------------------------------------------------------------------
// Fused pre-pass: blocks [0,8192) convert x fp32->f16; blocks [8192,9216)
// transpose W (fp32 [k][n]) -> wt f16 [z][n][k]. Independent outputs, one
// launch instead of two (saves a launch gap).
__global__ __launch_bounds__(256) void k_pre(const float* __restrict__ x,
                                             const float* __restrict__ Wq,
                                             const float* __restrict__ Wk,
                                             const float* __restrict__ Wv,
                                             const float* __restrict__ Wr,
                                             _Float16* __restrict__ xh,
                                             _Float16* __restrict__ wt) {
    __shared__ float t[64][65];
    const int tid = threadIdx.x;
    if (blockIdx.x < 8192) {
        size_t i = (size_t)blockIdx.x * 256 + tid;
        float4 v = ((const float4*)x)[i];
        half4_t h;
        h[0] = (_Float16)v.x; h[1] = (_Float16)v.y;
        h[2] = (_Float16)v.z; h[3] = (_Float16)v.w;
        ((half4_t*)xh)[i] = h;
        return;
    }
    const int bb = blockIdx.x - 8192;          // 0..1023
    const int z = bb >> 8;                     // 4 weights x 256 tiles
    const int idx = bb & 255;
    const int n0 = (idx & 15) * 64, k0 = (idx >> 4) * 64;
    const float* W = (z == 0) ? Wq : (z == 1) ? Wk : (z == 2) ? Wv : Wr;
    _Float16* o = wt + (size_t)z * U_DIM * U_DIM;
    for (int c = tid; c < 1024; c += 256) {
        int kk = c >> 4, nn = (c & 15) * 4;
        float4 v = *(const float4*)&W[(size_t)(k0 + kk) * U_DIM + n0 + nn];
        t[kk][nn] = v.x; t[kk][nn + 1] = v.y; t[kk][nn + 2] = v.z; t[kk][nn + 3] = v.w;
    }
    __syncthreads();
    for (int c = tid; c < 512; c += 256) {
        int nn = c >> 3, ks = (c & 7) * 8;
        half8_t h;
        for (int i = 0; i < 8; i++) h[i] = (_Float16)t[ks + i][nn];
        *(half8_t*)&o[(size_t)(n0 + nn) * U_DIM + k0 + ks] = h;
    }
}

// ---------------------------------------------------------------------------
// C = relu(X @ W_z + b_z), f16 row-major out. 128x128 tile; swizzled glds
// staging; XCD supertile remap. (R6 known-good version.)
__global__ __launch_bounds__(256) void k_qkvr_gemm(const _Float16* __restrict__ xh,
                                                   const _Float16* __restrict__ wt,
                                                   const float* __restrict__ bq,
                                                   const float* __restrict__ bk,
                                                   const float* __restrict__ bv,
                                                   const float* __restrict__ br,
                                                   _Float16* __restrict__ qh,
                                                   _Float16* __restrict__ kh,
                                                   _Float16* __restrict__ vh,
                                                   _Float16* __restrict__ resh) {
    const int b = blockIdx.x;
    const int xcd = b & 7, s = b >> 3;
    const int pair = xcd + 8 * (s & 3);       // (z,n) column pair, fixed per XCD slot
    const int m0 = (s >> 2) * 128;
    const int n0 = (pair & 7) * 128;
    const int z = pair >> 3;
    const _Float16* wz = wt + (size_t)z * U_DIM * U_DIM;

    __shared__ __align__(16) char AsB[8192];   // 8 chunks of 16 rows x 64B, swizzled
    __shared__ __align__(16) char BsB[8192];
    __shared__ __align__(16) _Float16 Cs[128][136];

    const int tid = threadIdx.x;
    const int wave = tid >> 6, lane = tid & 63;
    const int lrow = lane & 15, quad = lane >> 4;
    const int wm = (wave >> 1) * 64, wn = (wave & 1) * 64;
    const int lr4 = lane >> 2;
    const int sseg = ((lane & 3) ^ swz(lr4)) * 16;  // swizzled source segment
    const int rsw = (quad ^ swz(lrow)) * 16;        // swizzled read segment

    floatx4 acc[4][4];
    for (int i = 0; i < 4; i++)
        for (int j = 0; j < 4; j++) acc[i][j] = (floatx4)0.0f;

    const char* xb = (const char*)xh;
    const char* wb = (const char*)wz;

    for (int k0 = 0; k0 < U_DIM; k0 += 32) {
        for (int t = 0; t < 2; t++) {
            int c = wave * 2 + t;
            stage16(AsB + c * 1024,
                    xb + (size_t)(m0 + c * 16 + lr4) * 2048 + k0 * 2 + sseg, lane);
            stage16(BsB + c * 1024,
                    wb + (size_t)(n0 + c * 16 + lr4) * 2048 + k0 * 2 + sseg, lane);
        }
        __syncthreads();
        half8_t af[4], bf[4];
        for (int i = 0; i < 4; i++)
            af[i] = *(const half8_t*)(AsB + ((wave >> 1) * 4 + i) * 1024 + lrow * 64 + rsw);
        for (int j = 0; j < 4; j++)
            bf[j] = *(const half8_t*)(BsB + ((wave & 1) * 4 + j) * 1024 + lrow * 64 + rsw);
        for (int i = 0; i < 4; i++)
            for (int j = 0; j < 4; j++)
                acc[i][j] = __builtin_amdgcn_mfma_f32_16x16x32_f16(af[i], bf[j], acc[i][j], 0, 0, 0);
        __syncthreads();
    }

    const float* bias = (z == 0) ? bq : (z == 1) ? bk : (z == 2) ? bv : br;
    _Float16* dst = (z == 0) ? qh : (z == 1) ? kh : (z == 2) ? vh : resh;

    for (int i = 0; i < 4; i++) {
        for (int j = 0; j < 4; j++) {
            int col = wn + j * 16 + lrow;
            float bcol = bias[n0 + col];
            for (int r = 0; r < 4; r++) {
                float v = acc[i][j][r] + bcol;
                Cs[wm + i * 16 + quad * 4 + r][col] = (_Float16)(v > 0.f ? v : 0.f);
            }
        }
    }
    __syncthreads();
    for (int c = tid; c < 2048; c += 256) {
        int row = c >> 4, seg = (c & 15) * 8;
        *(half8_t*)&dst[(size_t)(m0 + row) * U_DIM + n0 + seg] = *(half8_t*)&Cs[row][seg];
    }
}

// ---------------------------------------------------------------------------
// v (f16 flat, read as [n][s][d] per raw reshape) -> vt (f16, [n][d][s])
__global__ __launch_bounds__(256) void k_transpose_v(const _Float16* __restrict__ vh,
                                                     _Float16* __restrict__ vt) {
    const int n = blockIdx.z;
    const int s0 = blockIdx.x * 64, d0 = blockIdx.y * 64;
    const _Float16* V = vh + (size_t)n * S_LEN * HD;
    _Float16* O = vt + (size_t)n * HD * S_LEN;
    __shared__ _Float16 t[64][72];
    const int tid = threadIdx.x;
    for (int c = tid; c < 512; c += 256) {
        int srow = c >> 3, off = (c & 7) * 8;
        *(half8_t*)&t[srow][off] = *(const half8_t*)&V[(size_t)(s0 + srow) * HD + d0 + off];
    }
    __syncthreads();
    for (int c = tid; c < 512; c += 256) {
        int drow = c >> 3, soff = (c & 7) * 8;
        half8_t h;
        for (int i = 0; i < 8; i++) h[i] = t[soff + i][drow];
        *(half8_t*)&O[(size_t)(d0 + drow) * S_LEN + s0 + soff] = h;
    }
}

// ---------------------------------------------------------------------------
// Fused attention v7: kv-tile 32, DOUBLE-BUFFERED K/V staging, ONE barrier
// per iteration. The glds for tile kt+1 is issued at the top of iteration kt
// and only drained by the barrier at the END of kt (~a full compute phase in
// flight) -> the vmcnt(0) drain that stalled v4 (R6) is hidden. Per-kv work
// (MFMA, exp, LDS fragment reads) identical to R6; swizzle math identical.
// S^T = K @ Q^T; packed P writes; unnormalized softmax p = exp2(s*C1 - 6)
// (constant shift cancels in O/l; q,k >= 0 post-relu).
__global__ __launch_bounds__(256, 2) void k_flash(const _Float16* __restrict__ qh,
                                                  const _Float16* __restrict__ kh,
                                                  const _Float16* __restrict__ vt,
                                                  _Float16* __restrict__ attnh) {
    const int head = blockIdx.x + 8 * (blockIdx.y & 3);
    const int m0 = (int)(blockIdx.y >> 2) * 128;
    const _Float16* Q = qh + (size_t)head * S_LEN * HD;
    const char* Kb = (const char*)(kh + (size_t)head * S_LEN * HD);
    const char* Vb = (const char*)(vt + (size_t)head * HD * S_LEN);

    // buf b at smem + b*16384: Ks 8KB (8 chunks) + Vs 8KB (8 chunks); Ps at 32768.
    __shared__ __align__(16) char smem[43008];
    _Float16* Ps = (_Float16*)(smem + 32768);  // [128 q][40 halves] (32 kv + pad)

    const int tid = threadIdx.x;
    const int w = tid >> 6, lane = tid & 63;
    const int lrow = lane & 15, quad = lane >> 4;
    const int lr4 = lane >> 2;
    const int sseg = ((lane & 3) ^ swz(lr4)) * 16;
    const int rsw = (quad ^ swz(lrow)) * 16;

    // Q fragments resident; wave w owns q rows m0+w*32..+31
    half8_t qf[2][4];
    for (int i = 0; i < 2; i++)
        for (int k0 = 0; k0 < 4; k0++)
            qf[i][k0] = *(const half8_t*)&Q[(size_t)(m0 + w * 32 + i * 16 + lrow) * HD + k0 * 32 + quad * 8];

    floatx4 acc_o[2][8];
    for (int i = 0; i < 2; i++)
        for (int j = 0; j < 8; j++) acc_o[i][j] = (floatx4)0.0f;
    float lp[2] = {0.0f, 0.0f};  // row-sums for q = w*32 + i*16 + lrow

    const float C1 = 0.12751742f;  // (1/sqrt(128)) * log2(e)

    // stage kv-tile kt into buffer b. Wave w stages K chunks {2w,2w+1} and
    // V chunks {2w,2w+1}. K chunk c: j=c&1 (kv half of 16), k0=c>>1 (d 64B).
    // V chunk c: d rows c*16.., full 64B tile row (32 kv).
#define STAGE(bsel, kt)                                                                   \
    for (int t = 0; t < 2; t++) {                                                         \
        int c = w * 2 + t;                                                                \
        stage16(smem + (bsel) * 16384 + c * 1024,                                         \
                Kb + (size_t)((kt) * 32 + (c & 1) * 16 + lr4) * 256 + (c >> 1) * 64 + sseg, lane); \
        stage16(smem + (bsel) * 16384 + 8192 + c * 1024,                                  \
                Vb + (size_t)(c * 16 + lr4) * 4096 + (kt) * 64 + sseg, lane);             \
    }

    STAGE(0, 0);
    __syncthreads();

    for (int kt = 0; kt < 64; ++kt) {
        const int cur = kt & 1;
        if (kt + 1 < 64) { STAGE(1 - cur, kt + 1); }
        const char* K = smem + cur * 16384;
        const char* V = smem + cur * 16384 + 8192;

        // scores: T[kv 16][q 16] tiles; lane holds kv=j*16+quad*4+r, q=lrow
        floatx4 acc_t[2][2];
        for (int i = 0; i < 2; i++)
            for (int j = 0; j < 2; j++) acc_t[i][j] = (floatx4)0.0f;
        for (int k0 = 0; k0 < 4; k0++)
            for (int j = 0; j < 2; j++) {
                half8_t kf = *(const half8_t*)(K + (k0 * 2 + j) * 1024 + lrow * 64 + rsw);
                for (int i = 0; i < 2; i++)
                    acc_t[i][j] = __builtin_amdgcn_mfma_f32_16x16x32_f16(kf, qf[i][k0], acc_t[i][j], 0, 0, 0);
            }

        // exp + packed P write (ds_write_b64: 4 consecutive kv per lane)
        for (int i = 0; i < 2; i++)
            for (int j = 0; j < 2; j++) {
                floatx4 sv = acc_t[i][j] * C1 - 6.0f;
                half4_t ph;
                float p0 = exp2f(sv[0]), p1 = exp2f(sv[1]);
                float p2 = exp2f(sv[2]), p3 = exp2f(sv[3]);
                ph[0] = (_Float16)p0; ph[1] = (_Float16)p1;
                ph[2] = (_Float16)p2; ph[3] = (_Float16)p3;
                lp[i] += (p0 + p1) + (p2 + p3);
                *(half4_t*)&Ps[(w * 32 + i * 16 + lrow) * 40 + j * 16 + quad * 4] = ph;
            }

        // PV: O[32 q x 128 d] += P[32 x 32] @ V[32 x 128] (one K=32 step)
        half8_t af[2];
        for (int i = 0; i < 2; i++)
            af[i] = *(const half8_t*)&Ps[(w * 32 + i * 16 + lrow) * 40 + quad * 8];
        for (int j = 0; j < 8; j++) {
            half8_t bv = *(const half8_t*)(V + j * 1024 + lrow * 64 + rsw);
            for (int i = 0; i < 2; i++)
                acc_o[i][j] = __builtin_amdgcn_mfma_f32_16x16x32_f16(af[i], bv, acc_o[i][j], 0, 0, 0);
        }
        __syncthreads();   // drains: LDS reads of buf[cur] + glds of buf[1-cur]
                           // (issued a full compute phase ago -> latency hidden)
    }

    // finish row sums (kv spread across quads), then per-O-row broadcast
    float inv[2][4];
    for (int i = 0; i < 2; i++) {
        lp[i] += __shfl_xor(lp[i], 16, 64);
        lp[i] += __shfl_xor(lp[i], 32, 64);
        for (int r = 0; r < 4; r++)
            inv[i][r] = 1.0f / __shfl(lp[i], quad * 4 + r, 64);
    }

    __syncthreads();
    _Float16* Os = (_Float16*)smem;  // [128][136]
    for (int i = 0; i < 2; i++)
        for (int j = 0; j < 8; j++)
            for (int r = 0; r < 4; r++)
                Os[(w * 32 + i * 16 + quad * 4 + r) * 136 + j * 16 + lrow] =
                    (_Float16)(acc_o[i][j][r] * inv[i][r]);
    __syncthreads();
    const size_t base = (size_t)head * S_LEN * HD;
    for (int c = tid; c < 2048; c += 256) {
        int row = c >> 4, seg = (c & 15) * 8;
        *(half8_t*)&attnh[base + (size_t)(m0 + row) * HD + seg] = *(half8_t*)&Os[row * 136 + seg];
    }
#undef STAGE
}

// ---------------------------------------------------------------------------
// out = LN(relu(attn + res)) * gamma + beta ; biased var, eps inside sqrt
__global__ __launch_bounds__(256) void k_ln(const _Float16* __restrict__ attnh,
                                            const _Float16* __restrict__ resh,
                                            const float* __restrict__ gamma,
                                            const float* __restrict__ beta,
                                            float* __restrict__ out) {
    const size_t row = blockIdx.x;
    const int tid = threadIdx.x;
    half4_t av = ((const half4_t*)(attnh + row * U_DIM))[tid];
    half4_t rv = ((const half4_t*)(resh + row * U_DIM))[tid];
    float o[4];
    float s1 = 0.f, s2 = 0.f;
    for (int i = 0; i < 4; i++) {
        o[i] = fmaxf((float)av[i] + (float)rv[i], 0.f);
        s1 += o[i];
        s2 += o[i] * o[i];
    }
    for (int off = 32; off; off >>= 1) {
        s1 += __shfl_xor(s1, off, 64);
        s2 += __shfl_xor(s2, off, 64);
    }
    __shared__ float red[8];
    const int wv = tid >> 6;
    if ((tid & 63) == 0) { red[wv] = s1; red[4 + wv] = s2; }
    __syncthreads();
    float ts1 = red[0] + red[1] + red[2] + red[3];
    float ts2 = red[4] + red[5] + red[6] + red[7];
    float mean = ts1 * (1.0f / 1024.0f);
    float var = ts2 * (1.0f / 1024.0f) - mean * mean;
    float rstd = rsqrtf(var + 1e-8f);
    float4 gv = ((const float4*)gamma)[tid];
    float4 bv = ((const float4*)beta)[tid];
    float4 ov;
    ov.x = gv.x * (o[0] - mean) * rstd + bv.x;
    ov.y = gv.y * (o[1] - mean) * rstd + bv.y;
    ov.z = gv.z * (o[2] - mean) * rstd + bv.z;
    ov.w = gv.w * (o[3] - mean) * rstd + bv.w;
    ((float4*)(out + row * U_DIM))[tid] = ov;
}

// ---------------------------------------------------------------------------
extern "C" void kernel_launch(void* const* d_in, const int* in_sizes, int n_in,
                              void* d_out, int out_size, void* d_ws, size_t ws_size,
                              hipStream_t stream) {
    const float* x     = (const float*)d_in[0];
    const float* Wq    = (const float*)d_in[1];
    const float* bq    = (const float*)d_in[2];
    const float* Wk    = (const float*)d_in[3];
    const float* bk    = (const float*)d_in[4];
    const float* Wv    = (const float*)d_in[5];
    const float* bv    = (const float*)d_in[6];
    const float* Wr    = (const float*)d_in[7];
    const float* br    = (const float*)d_in[8];
    const float* gamma = (const float*)d_in[9];
    const float* beta  = (const float*)d_in[10];
    float* out = (float*)d_out;

    char* p = (char*)d_ws;
    _Float16* xh = (_Float16*)p;    p += (size_t)M_TOT * U_DIM * 2;       // 16 MB
    _Float16* wt = (_Float16*)p;    p += (size_t)4 * U_DIM * U_DIM * 2;   //  8 MB
    _Float16* qh = (_Float16*)p;    p += (size_t)M_TOT * U_DIM * 2;       // 16 MB
    _Float16* kh = (_Float16*)p;    p += (size_t)M_TOT * U_DIM * 2;       // 16 MB
    _Float16* vh = (_Float16*)p;    p += (size_t)M_TOT * U_DIM * 2;       // 16 MB
    _Float16* vt = (_Float16*)p;    p += (size_t)M_TOT * U_DIM * 2;       // 16 MB
    _Float16* resh = (_Float16*)p;  p += (size_t)M_TOT * U_DIM * 2;       // 16 MB
    _Float16* attnh = (_Float16*)p;                                       // 16 MB

    k_pre<<<9216, 256, 0, stream>>>(x, Wq, Wk, Wv, Wr, xh, wt);
    k_qkvr_gemm<<<2048, 256, 0, stream>>>(xh, wt, bq, bk, bv, br, qh, kh, vh, resh);
    k_transpose_v<<<dim3(32, 2, 32), 256, 0, stream>>>(vh, vt);
    k_flash<<<dim3(8, 64), 256, 0, stream>>>(qh, kh, vt, attnh);
    k_ln<<<8192, 256, 0, stream>>>(attnh, resh, gamma, beta, out);
}